// Round 6
// baseline (335.998 us; speedup 1.0000x reference)
//
#include <hip/hip_runtime.h>
#include <math.h>

#define F 128
#define THREEF 384
#define N_RBF 20
#define CUTOFF 5.0f
#define CAP 64

// ---------------------------------------------------------------------------
// Kernel 1: phi = silu(h @ W1 + b1) @ W2 + b2, stored as 3 planes [c][node][f]
// ---------------------------------------------------------------------------
__global__ __launch_bounds__(256) void mlp_kernel(
    const float* __restrict__ h, const float* __restrict__ W1,
    const float* __restrict__ b1, const float* __restrict__ W2,
    const float* __restrict__ b2, float* __restrict__ phi, int N)
{
    __shared__ float sh_h[16 * F];
    __shared__ float sh_t[16 * F];
    const int tid   = threadIdx.x;
    const int node0 = blockIdx.x * 16;

    {
        const float4* src = (const float4*)(h + (size_t)node0 * F);
        float4* dst = (float4*)sh_h;
        dst[tid]       = src[tid];
        dst[tid + 256] = src[tid + 256];
    }
    __syncthreads();

    const int j2 = tid & 63;
    const int r0 = (tid >> 6) * 4;

    {
        float acc[4][2];
        const float bb0 = b1[j2], bb1 = b1[j2 + 64];
        #pragma unroll
        for (int r = 0; r < 4; ++r) { acc[r][0] = bb0; acc[r][1] = bb1; }
        for (int k4 = 0; k4 < F; k4 += 4) {
            float4 a[4];
            #pragma unroll
            for (int r = 0; r < 4; ++r)
                a[r] = *(const float4*)&sh_h[(r0 + r) * F + k4];
            #pragma unroll
            for (int kk = 0; kk < 4; ++kk) {
                const float w0  = W1[(k4 + kk) * F + j2];
                const float w1v = W1[(k4 + kk) * F + j2 + 64];
                #pragma unroll
                for (int r = 0; r < 4; ++r) {
                    const float av = ((const float*)&a[r])[kk];
                    acc[r][0] = fmaf(av, w0,  acc[r][0]);
                    acc[r][1] = fmaf(av, w1v, acc[r][1]);
                }
            }
        }
        #pragma unroll
        for (int r = 0; r < 4; ++r) {
            const float x0 = acc[r][0], x1 = acc[r][1];
            sh_t[(r0 + r) * F + j2]      = x0 / (1.0f + __expf(-x0));
            sh_t[(r0 + r) * F + j2 + 64] = x1 / (1.0f + __expf(-x1));
        }
    }
    __syncthreads();

    {
        float acc[4][6];
        #pragma unroll
        for (int c = 0; c < 6; ++c) {
            const float bb = b2[j2 + c * 64];
            #pragma unroll
            for (int r = 0; r < 4; ++r) acc[r][c] = bb;
        }
        for (int k4 = 0; k4 < F; k4 += 4) {
            float4 a[4];
            #pragma unroll
            for (int r = 0; r < 4; ++r)
                a[r] = *(const float4*)&sh_t[(r0 + r) * F + k4];
            #pragma unroll
            for (int kk = 0; kk < 4; ++kk) {
                float w[6];
                #pragma unroll
                for (int c = 0; c < 6; ++c)
                    w[c] = W2[(k4 + kk) * THREEF + j2 + c * 64];
                #pragma unroll
                for (int r = 0; r < 4; ++r) {
                    const float av = ((const float*)&a[r])[kk];
                    #pragma unroll
                    for (int c = 0; c < 6; ++c)
                        acc[r][c] = fmaf(av, w[c], acc[r][c]);
                }
            }
        }
        #pragma unroll
        for (int r = 0; r < 4; ++r) {
            #pragma unroll
            for (int c = 0; c < 6; ++c) {
                const int col = j2 + c * 64;
                const int p   = col >> 7;
                const int fc  = col & 127;
                phi[(size_t)p * N * F + (size_t)(node0 + r0 + r) * F + fc] = acc[r][c];
            }
        }
    }
}

// ---------------------------------------------------------------------------
// Build: slot via atomic; eid scatter (4B); pack written LINEARLY by edge
// (coalesced 32B). pack[e] = {s1, 2cos(x), fcut, ux, uy, uz, src_bits, 0}
// ---------------------------------------------------------------------------
__global__ __launch_bounds__(256) void build_kernel(
    const float* __restrict__ d_ij, const float* __restrict__ unit_r,
    const int* __restrict__ nbrs, int* __restrict__ cnt,
    int* __restrict__ eid, float* __restrict__ pack, int E)
{
    int e = blockIdx.x * 256 + threadIdx.x;
    if (e >= E) return;
    const int dst = nbrs[2 * e];
    const int src = nbrs[2 * e + 1];
    const int slot = atomicAdd(&cnt[dst], 1);
    if (slot < CAP) eid[dst * CAP + slot] = e;

    const float d = d_ij[e];
    const float x = (float)M_PI * d * (1.0f / CUTOFF);
    float sx, cx;
    __sincosf(x, &sx, &cx);
    const float fcut = (d < CUTOFF) ? 0.5f * (cx + 1.0f) : 0.0f;
    float4 q0, q1;
    q0.x = sx * fcut / d;     // s1 (rbff_1); recurrence preserves fcut/d scale
    q0.y = 2.0f * cx;
    q0.z = fcut;
    q0.w = unit_r[3 * e + 0];
    q1.x = unit_r[3 * e + 1];
    q1.y = unit_r[3 * e + 2];
    q1.z = __int_as_float(src);
    q1.w = 0.0f;
    float4* pk = (float4*)(pack + (size_t)e * 8);
    pk[0] = q0;
    pk[1] = q1;
}

// ---------------------------------------------------------------------------
// Gather: block per dst node, thread = feature f. 4 edges per inner tile so
// each Wr load is amortized over 12 FMAs (no reliance on 60-reg residency).
// Pad edges get s1=0, fcut=0 -> zero contribution, src stays in-bounds.
// ---------------------------------------------------------------------------
__global__ __launch_bounds__(128) void gather_kernel(
    const float* __restrict__ phi,       // 3 planes of (N,128)
    const float* __restrict__ v_i,       // (N,128,3)
    const float* __restrict__ Wr,        // (20,384)
    const float* __restrict__ br,        // (384)
    const int*   __restrict__ cnt,       // (N)
    const int*   __restrict__ eid,       // (N,CAP)
    const float* __restrict__ pack,      // (E,8)
    float* __restrict__ dh,              // (N,128)
    float* __restrict__ dv,              // (N,128,3)
    int N)
{
    const int node = blockIdx.x;
    const int f    = threadIdx.x;

    const float br0 = br[f], br1 = br[f + 128], br2 = br[f + 256];

    const int deg0 = cnt[node];
    const int deg  = deg0 < CAP ? deg0 : CAP;
    const int* my_eid = eid + node * CAP;

    const float* phi0 = phi;
    const float* phi1 = phi + (size_t)N * F;
    const float* phi2 = phi + (size_t)2 * N * F;

    const float* wr0 = Wr + f;          // wr0[n*THREEF]
    const float* wr1 = Wr + f + 128;
    const float* wr2 = Wr + f + 256;

    float dh_acc = 0.0f, dv0 = 0.0f, dv1 = 0.0f, dv2 = 0.0f;

    for (int i0 = 0; i0 < deg; i0 += 4) {
        float4 q0[4], q1[4];
        int    srcs[4];

        #pragma unroll
        for (int j = 0; j < 4; ++j) {
            const int idx = i0 + j;
            const int e = __builtin_amdgcn_readfirstlane(
                              my_eid[idx < deg ? idx : 0]);
            const float4* pkj = (const float4*)(pack + (size_t)e * 8);
            float4 a0 = pkj[0];
            float4 a1 = pkj[1];
            if (idx >= deg) { a0.x = 0.0f; a0.z = 0.0f; }   // kill contribution
            q0[j] = a0;
            q1[j] = a1;
            srcs[j] = __builtin_amdgcn_readfirstlane(__float_as_int(a1.z));
        }

        float a[4][3], rp[4], rc[4], twoc[4];
        #pragma unroll
        for (int j = 0; j < 4; ++j) {
            const float fc = q0[j].z;
            a[j][0] = br0 * fc;
            a[j][1] = br1 * fc;
            a[j][2] = br2 * fc;
            rp[j]   = 0.0f;
            rc[j]   = q0[j].x;
            twoc[j] = q0[j].y;
        }

        #pragma unroll 4
        for (int n = 0; n < N_RBF; ++n) {
            const float w0 = wr0[n * THREEF];
            const float w1 = wr1[n * THREEF];
            const float w2 = wr2[n * THREEF];
            #pragma unroll
            for (int j = 0; j < 4; ++j) {
                a[j][0] = fmaf(rc[j], w0, a[j][0]);
                a[j][1] = fmaf(rc[j], w1, a[j][1]);
                a[j][2] = fmaf(rc[j], w2, a[j][2]);
                const float rn = fmaf(twoc[j], rc[j], -rp[j]);
                rp[j] = rc[j];
                rc[j] = rn;
            }
        }

        #pragma unroll
        for (int j = 0; j < 4; ++j) {
            const int src = srcs[j];
            const float f1 = phi0[(size_t)src * F + f] * a[j][0];
            const float f2 = phi1[(size_t)src * F + f] * a[j][1];
            const float f3 = phi2[(size_t)src * F + f] * a[j][2];

            dh_acc += f3;

            const float* vs = v_i + (size_t)src * THREEF + 3 * f;
            dv0 = fmaf(f1, q0[j].w, fmaf(f2, vs[0], dv0));
            dv1 = fmaf(f1, q1[j].x, fmaf(f2, vs[1], dv1));
            dv2 = fmaf(f1, q1[j].y, fmaf(f2, vs[2], dv2));
        }
    }

    dh[(size_t)node * F + f] = dh_acc;
    float* dvp = dv + (size_t)node * THREEF + 3 * f;
    dvp[0] = dv0;
    dvp[1] = dv1;
    dvp[2] = dv2;
}

extern "C" void kernel_launch(void* const* d_in, const int* in_sizes, int n_in,
                              void* d_out, int out_size, void* d_ws, size_t ws_size,
                              hipStream_t stream) {
    const float* h_i    = (const float*)d_in[0];
    const float* v_i    = (const float*)d_in[1];
    const float* d_ij   = (const float*)d_in[2];
    const float* unit_r = (const float*)d_in[3];
    const int*   nbrs   = (const int*)  d_in[4];
    const float* W1     = (const float*)d_in[5];
    const float* b1     = (const float*)d_in[6];
    const float* W2     = (const float*)d_in[7];
    const float* b2     = (const float*)d_in[8];
    const float* Wr     = (const float*)d_in[9];
    const float* br     = (const float*)d_in[10];

    const int N = in_sizes[0] / F;       // 20000
    const int E = in_sizes[2];           // 320000

    float* dh = (float*)d_out;              // (N,128)
    float* dv = dh + (size_t)N * F;         // (N,128,3)

    // workspace: phi (3*N*128) | pack (E*8) | cnt (N) | eid (N*CAP)
    float* phi  = (float*)d_ws;
    float* pack = phi + (size_t)3 * N * F;
    int*   cnt  = (int*)(pack + (size_t)E * 8);
    int*   eid  = cnt + N;

    hipMemsetAsync(cnt, 0, (size_t)N * sizeof(int), stream);

    mlp_kernel<<<(N + 15) / 16, 256, 0, stream>>>(h_i, W1, b1, W2, b2, phi, N);
    build_kernel<<<(E + 255) / 256, 256, 0, stream>>>(d_ij, unit_r, nbrs, cnt,
                                                      eid, pack, E);
    gather_kernel<<<N, 128, 0, stream>>>(phi, v_i, Wr, br, cnt, eid, pack,
                                         dh, dv, N);
}